// Round 9
// baseline (135.973 us; speedup 1.0000x reference)
//
#include <hip/hip_runtime.h>

#define N_NODES 50000
#define N_EDGES 800000
#define D 128
#define CAP 64
#define NPB 512        // nodes per bin: bin = dst >> 9
#define NBIN 98        // ceil(50000/512)
#define BIN_CAP 12288  // per-bin edge capacity (mean 8163)
#define EPB 4096       // edges per binp block

typedef __attribute__((ext_vector_type(8))) short s16x8;
typedef __attribute__((ext_vector_type(8))) unsigned short u16x8;
typedef __attribute__((ext_vector_type(4))) unsigned short u16x4;
typedef __attribute__((ext_vector_type(4))) float f32x4;

__device__ __forceinline__ unsigned short f2bf(float f) {
    unsigned u = __builtin_bit_cast(unsigned, f);
    return (unsigned short)((u + 0x7FFFu + ((u >> 16) & 1u)) >> 16);
}
__device__ __forceinline__ float bf2f(unsigned short h) {
    return __builtin_bit_cast(float, (unsigned)h << 16);
}

__device__ __forceinline__ int load_src(const int* ei, int is32, int e) {
    return is32 ? ei[e] : ei[2 * e];
}
__device__ __forceinline__ int load_dst(const int* ei, int is32, int e) {
    return is32 ? ei[N_EDGES + e] : ei[2 * N_EDGES + 2 * e];
}

// ---------------------------------------------------------------------------
// Merged prep: blocks 0..3124 = x->bf16; 3125..3380 = W tables (bf16 RN,
// layout [col(128)][k(256)]); 3381 = zero bin_cnt + ei dtype detect.
__global__ void prep_kernel(const float* __restrict__ x, const int* __restrict__ ei,
                            const float* __restrict__ W1l, const float* __restrict__ W1r,
                            const float* __restrict__ W2l, const float* __restrict__ W2r,
                            unsigned short* __restrict__ xb,
                            unsigned short* __restrict__ wt1,
                            unsigned short* __restrict__ wt2,
                            int* __restrict__ flag, int* __restrict__ bin_cnt) {
    int b = blockIdx.x;
    if (b < 3125) {
        int t = b * 256 + threadIdx.x;  // t < 800000 == 3125*256
        float4 a = *(const float4*)(x + (size_t)t * 8);
        float4 c = *(const float4*)(x + (size_t)t * 8 + 4);
        u16x8 o;
        o[0] = f2bf(a.x); o[1] = f2bf(a.y); o[2] = f2bf(a.z); o[3] = f2bf(a.w);
        o[4] = f2bf(c.x); o[5] = f2bf(c.y); o[6] = f2bf(c.z); o[7] = f2bf(c.w);
        *(u16x8*)(xb + (size_t)t * 8) = o;
    } else if (b < 3381) {
        int idx = b - 3125;  // 0..255
        int layer = idx >> 7;
        int c = idx & 127;
        int k = threadIdx.x;
        const float* Wl = layer ? W2l : W1l;
        const float* Wr = layer ? W2r : W1r;
        unsigned short* wt = layer ? wt2 : wt1;
        float v = (k < 128) ? Wl[(size_t)k * 128 + c] : Wr[(size_t)(k - 128) * 128 + c];
        wt[c * 256 + k] = f2bf(v);
    } else {
        if (threadIdx.x < 128) bin_cnt[threadIdx.x] = 0;
        __shared__ int any;
        if (threadIdx.x == 0) any = 0;
        __syncthreads();
        if (ei[2 * threadIdx.x + 1] != 0) atomicOr(&any, 1);
        __syncthreads();
        if (threadIdx.x == 0) flag[0] = any;
    }
}

// ---------------------------------------------------------------------------
// Pass 1: bin edges by dst>>9 into 98 global bins; packed (dst16|src16).
__global__ __launch_bounds__(256) void binp_kernel(const int* __restrict__ ei,
                                                   const int* __restrict__ flag,
                                                   int* __restrict__ bin_cnt,
                                                   unsigned* __restrict__ bins) {
    __shared__ unsigned sBuf[EPB];
    __shared__ int bcnt[128], brun[128], bpos[128], gbase[128];
    int tid = threadIdx.x;
    int blk = blockIdx.x;
    int e0 = blk * EPB + tid * 16;
    int nblk = N_EDGES - blk * EPB;
    if (nblk > EPB) nblk = EPB;
    bool valid = (tid * 16) < nblk;
    if (tid < 128) bcnt[tid] = 0;
    __syncthreads();
    unsigned packed[16];
    if (valid) {
        int is32 = flag[0];
        if (is32) {
            const int4* ps = (const int4*)(ei + e0);
            const int4* pd = (const int4*)(ei + N_EDGES + e0);
#pragma unroll
            for (int q = 0; q < 4; ++q) {
                int4 s = ps[q], d = pd[q];
                packed[q * 4 + 0] = ((unsigned)d.x << 16) | (unsigned)s.x;
                packed[q * 4 + 1] = ((unsigned)d.y << 16) | (unsigned)s.y;
                packed[q * 4 + 2] = ((unsigned)d.z << 16) | (unsigned)s.z;
                packed[q * 4 + 3] = ((unsigned)d.w << 16) | (unsigned)s.w;
            }
        } else {
            const int4* ps = (const int4*)(ei + 2 * (size_t)e0);
            const int4* pd = (const int4*)(ei + 2 * (size_t)N_EDGES + 2 * (size_t)e0);
#pragma unroll
            for (int q = 0; q < 8; ++q) {
                int4 s = ps[q], d = pd[q];
                packed[q * 2 + 0] = ((unsigned)d.x << 16) | (unsigned)s.x;
                packed[q * 2 + 1] = ((unsigned)d.z << 16) | (unsigned)s.z;
            }
        }
#pragma unroll
        for (int k = 0; k < 16; ++k) atomicAdd(&bcnt[packed[k] >> 25], 1);
    }
    __syncthreads();
    if (tid < 64) {
        int a = bcnt[2 * tid], b = bcnt[2 * tid + 1];
        int s = a + b;
        int incl = s;
#pragma unroll
        for (int o = 1; o < 64; o <<= 1) {
            int t = __shfl_up(incl, o, 64);
            if (tid >= o) incl += t;
        }
        int pref = incl - s;
        brun[2 * tid] = pref;
        brun[2 * tid + 1] = pref + a;
        bpos[2 * tid] = pref;
        bpos[2 * tid + 1] = pref + a;
    }
    __syncthreads();
    if (valid) {
#pragma unroll
        for (int k = 0; k < 16; ++k) {
            int b = packed[k] >> 25;
            int slot = atomicAdd(&bpos[b], 1);
            sBuf[slot] = packed[k];
        }
    }
    __syncthreads();
    if (tid < 128) {
        int n = bcnt[tid];
        gbase[tid] = n > 0 ? atomicAdd(&bin_cnt[tid], n) : 0;
    }
    __syncthreads();
    for (int i = tid; i < nblk; i += 256) {
        unsigned p = sBuf[i];
        int b = p >> 25;
        int gpos = gbase[b] + (i - brun[b]);
        if (gpos < BIN_CAP) bins[(size_t)b * BIN_CAP + gpos] = p;
    }
}

// Pass 2: one block per bin; buckets in LDS; dense coalesced write-out.
__global__ __launch_bounds__(256) void unbin_kernel(const int* __restrict__ bin_cnt,
                                                    const unsigned* __restrict__ bins,
                                                    int* __restrict__ cnt,
                                                    unsigned short* __restrict__ srcs16) {
    __shared__ unsigned short buck[NPB * CAP];
    __shared__ int lcnt[NPB];
    int tid = threadIdx.x;
    int bn = blockIdx.x;
    int nbase = bn * NPB;
    for (int i = tid; i < NPB; i += 256) lcnt[i] = 0;
    __syncthreads();
    int nE = bin_cnt[bn];
    if (nE > BIN_CAP) nE = BIN_CAP;
    for (int i = tid; i < nE; i += 256) {
        unsigned p = bins[(size_t)bn * BIN_CAP + i];
        int local = (int)(p >> 16) - nbase;
        if ((unsigned)local < NPB) {
            int slot = atomicAdd(&lcnt[local], 1);
            if (slot < CAP) buck[local * CAP + slot] = (unsigned short)(p & 0xFFFFu);
        }
    }
    __syncthreads();
    int nlim = N_NODES - nbase;
    if (nlim > NPB) nlim = NPB;
    const uint4* sb = (const uint4*)buck;
    uint4* go = (uint4*)(srcs16 + (size_t)nbase * CAP);
    int n4 = nlim * 8;
    for (int i = tid; i < n4; i += 256) go[i] = sb[i];
    for (int i = tid; i < nlim; i += 256) cnt[nbase + i] = lcnt[i];
}

// ---------------------------------------------------------------------------
// Gather-mean, 2 nodes per wave: 8 independent 1 KB gathers in flight/iter.
// int2 degree load; both index buckets preloaded; shfl broadcasts only.
__global__ __launch_bounds__(256) void aggp_kernel(const unsigned short* __restrict__ feat,
                                                   const int* __restrict__ cnt,
                                                   const unsigned short* __restrict__ srcs16,
                                                   unsigned short* __restrict__ agg) {
    int pair = blockIdx.x * 4 + (threadIdx.x >> 6);
    int n0 = pair * 2;
    if (n0 >= N_NODES) return;
    int lane = threadIdx.x & 63;
    int q = lane >> 4;
    int c16 = lane & 15;
    int2 dd = *(const int2*)(cnt + n0);
    int idx0 = srcs16[(size_t)n0 * CAP + lane];
    int idx1 = srcs16[(size_t)(n0 + 1) * CAP + lane];
    int d0 = dd.x < CAP ? dd.x : CAP;
    int d1 = dd.y < CAP ? dd.y : CAP;
    int dmax = d0 > d1 ? d0 : d1;
    float acc0[8] = {}, acc1[8] = {};
    for (int j = 0; j < dmax; j += 16) {
        int e0[4], e1[4];
        float m0[4], m1[4];
#pragma unroll
        for (int u = 0; u < 4; ++u) {
            int jj = j + u * 4 + q;
            int es0 = __shfl(idx0, jj, 64);
            int es1 = __shfl(idx1, jj, 64);
            bool v0 = jj < d0, v1 = jj < d1;
            e0[u] = v0 ? es0 : 0;
            m0[u] = v0 ? 1.f : 0.f;
            e1[u] = v1 ? es1 : 0;
            m1[u] = v1 ? 1.f : 0.f;
        }
        u16x8 v0[4], v1[4];
#pragma unroll
        for (int u = 0; u < 4; ++u) {
            v0[u] = *((const u16x8*)(feat + (size_t)e0[u] * D) + c16);
            v1[u] = *((const u16x8*)(feat + (size_t)e1[u] * D) + c16);
        }
#pragma unroll
        for (int u = 0; u < 4; ++u)
#pragma unroll
            for (int i = 0; i < 8; ++i) {
                acc0[i] += bf2f((unsigned short)v0[u][i]) * m0[u];
                acc1[i] += bf2f((unsigned short)v1[u][i]) * m1[u];
            }
    }
#pragma unroll
    for (int i = 0; i < 8; ++i) {
        acc0[i] += __shfl_xor(acc0[i], 16, 64);
        acc0[i] += __shfl_xor(acc0[i], 32, 64);
        acc1[i] += __shfl_xor(acc1[i], 16, 64);
        acc1[i] += __shfl_xor(acc1[i], 32, 64);
    }
    if (q == 0) {
        float s0 = dd.x > 0 ? 1.f / (float)dd.x : 0.f;
        float s1 = dd.y > 0 ? 1.f / (float)dd.y : 0.f;
        u16x8 o0, o1;
#pragma unroll
        for (int i = 0; i < 8; ++i) {
            o0[i] = f2bf(acc0[i] * s0);
            o1[i] = f2bf(acc1[i] * s1);
        }
        *((u16x8*)(agg + (size_t)n0 * D) + c16) = o0;
        *((u16x8*)(agg + (size_t)(n0 + 1) * D) + c16) = o1;
    }
}

// ---------------------------------------------------------------------------
// mm3: C[r] = Agb[r] @ W[0:128] + Rootb[r] @ W[128:256] + bias (+relu MODE1)
// Single-bf16 W (RN), held ENTIRELY in registers (16 frags = 64 VGPR/lane),
// preloaded before the A-staging barrier -> MFMA loop has zero global loads.
template <int MODE>
__global__ __launch_bounds__(256) void mm3_kernel(const unsigned short* __restrict__ Agb,
                                                  const unsigned short* __restrict__ Rootb,
                                                  const unsigned short* __restrict__ Wt,
                                                  const float* __restrict__ bias,
                                                  float* __restrict__ C,
                                                  unsigned short* __restrict__ Cb) {
    __shared__ __align__(16) unsigned short sA[2][32][128];
    int r0 = blockIdx.x * 32;
    int tid = threadIdx.x;
    int lane = tid & 63, wid = tid >> 6;
    int l15 = lane & 15, khalf = lane >> 4;

    // ---- preload all B fragments for this wave's 32 cols (issue FIRST)
    s16x8 bF[2][4][2];
#pragma unroll
    for (int p = 0; p < 2; ++p)
#pragma unroll
        for (int kc2 = 0; kc2 < 4; ++kc2)
#pragma unroll
            for (int nf = 0; nf < 2; ++nf) {
                int cc = wid * 32 + nf * 16 + l15;
                bF[p][kc2][nf] = *(const s16x8*)(Wt + (size_t)cc * 256 + p * 128 +
                                                 kc2 * 32 + khalf * 8);
            }

    // ---- stage both A panels (coalesced 32 B/thread/panel)
    {
        int r = tid >> 3;   // 0..31
        int kq = tid & 7;   // 0..7, 16 ushorts each
        int row = r0 + r;
        u16x8 a0, a1, x0, x1;
        if (row < N_NODES) {
            const u16x8* pa = (const u16x8*)(Agb + (size_t)row * D + kq * 16);
            a0 = pa[0]; a1 = pa[1];
            const u16x8* pr = (const u16x8*)(Rootb + (size_t)row * D + kq * 16);
            x0 = pr[0]; x1 = pr[1];
        } else {
            u16x8 z = {};
            a0 = z; a1 = z; x0 = z; x1 = z;
        }
        int c0 = (kq * 2) ^ (r & 7), c1 = (kq * 2 + 1) ^ (r & 7);
        *(u16x8*)&sA[0][r][c0 * 8] = a0;
        *(u16x8*)&sA[0][r][c1 * 8] = a1;
        *(u16x8*)&sA[1][r][c0 * 8] = x0;
        *(u16x8*)&sA[1][r][c1 * 8] = x1;
    }
    __syncthreads();

    // ---- MFMA: p=0 agg (k 0..127), p=1 root (k 128..255); pure LDS+MFMA
    f32x4 acc[2][2] = {};
#pragma unroll
    for (int p = 0; p < 2; ++p)
#pragma unroll
        for (int kc2 = 0; kc2 < 4; ++kc2) {
            s16x8 aF[2];
#pragma unroll
            for (int mf = 0; mf < 2; ++mf) {
                int rr = mf * 16 + l15;
                int chunk = (kc2 * 4 + khalf) ^ (rr & 7);
                aF[mf] = *(const s16x8*)&sA[p][rr][chunk * 8];
            }
#pragma unroll
            for (int nf = 0; nf < 2; ++nf)
#pragma unroll
                for (int mf = 0; mf < 2; ++mf)
                    acc[mf][nf] = __builtin_amdgcn_mfma_f32_16x16x32_bf16(
                        aF[mf], bF[p][kc2][nf], acc[mf][nf], 0, 0, 0);
        }

    // ---- epilogue: C/D layout col=lane&15, row=(lane>>4)*4+reg (m89-verified)
#pragma unroll
    for (int mf = 0; mf < 2; ++mf)
#pragma unroll
        for (int nf = 0; nf < 2; ++nf) {
            int col = wid * 32 + nf * 16 + l15;
            float b = bias[col];
#pragma unroll
            for (int r = 0; r < 4; ++r) {
                int row = r0 + mf * 16 + khalf * 4 + r;
                if (row < N_NODES) {
                    float o = acc[mf][nf][r] + b;
                    if (MODE == 1) {
                        o = fmaxf(o, 0.f);
                        Cb[(size_t)row * D + col] = f2bf(o);
                    } else {
                        C[(size_t)row * D + col] = o;
                    }
                }
            }
        }
}

// ---------------------------------------------------------------------------
// ---- compact CSR fallback kernels (only if ws too small) -------------------
__global__ void initc_kernel(const int* __restrict__ ei, int* __restrict__ flag,
                             int* __restrict__ cnt) {
    int i = blockIdx.x * 256 + threadIdx.x;
    if (i < 50048) cnt[i] = 0;
    if (blockIdx.x == 0) {
        __shared__ int any;
        if (threadIdx.x == 0) any = 0;
        __syncthreads();
        if (ei[2 * threadIdx.x + 1] != 0) atomicOr(&any, 1);
        __syncthreads();
        if (threadIdx.x == 0) flag[0] = any;
    }
}

__global__ void prep_wf_kernel(const float* __restrict__ W1l, const float* __restrict__ W1r,
                               const float* __restrict__ W2l, const float* __restrict__ W2r,
                               unsigned short* __restrict__ wt1,
                               unsigned short* __restrict__ wt2) {
    int layer = blockIdx.x >> 7;
    int c = blockIdx.x & 127;
    int k = threadIdx.x;
    const float* Wl = layer ? W2l : W1l;
    const float* Wr = layer ? W2r : W1r;
    unsigned short* wt = layer ? wt2 : wt1;
    float v = (k < 128) ? Wl[(size_t)k * 128 + c] : Wr[(size_t)(k - 128) * 128 + c];
    wt[c * 256 + k] = f2bf(v);
}

__global__ void tobf_kernel(const float* __restrict__ in, unsigned short* __restrict__ out,
                            int n8) {
    int t = blockIdx.x * 256 + threadIdx.x;
    if (t >= n8) return;
    float4 a = *(const float4*)(in + (size_t)t * 8);
    float4 b = *(const float4*)(in + (size_t)t * 8 + 4);
    u16x8 o;
    o[0] = f2bf(a.x); o[1] = f2bf(a.y); o[2] = f2bf(a.z); o[3] = f2bf(a.w);
    o[4] = f2bf(b.x); o[5] = f2bf(b.y); o[6] = f2bf(b.z); o[7] = f2bf(b.w);
    *(u16x8*)(out + (size_t)t * 8) = o;
}

__global__ void hist_kernel(const int* __restrict__ ei, const int* __restrict__ flag,
                            int* __restrict__ cnt) {
    int e = blockIdx.x * blockDim.x + threadIdx.x;
    if (e >= N_EDGES) return;
    int is32 = flag[0];
    atomicAdd(&cnt[load_dst(ei, is32, e)], 1);
}

__global__ __launch_bounds__(1024) void scan_kernel(int* __restrict__ cnt_cur,
                                                    int* __restrict__ off) {
    __shared__ int wsum[16];
    __shared__ int woff[16];
    __shared__ int carry;
    __shared__ int tile_tot;
    int lane = threadIdx.x & 63;
    int wid = threadIdx.x >> 6;
    if (threadIdx.x == 0) carry = 0;
    __syncthreads();
    for (int base = 0; base < N_NODES; base += 1024) {
        int i = base + threadIdx.x;
        int v = (i < N_NODES) ? cnt_cur[i] : 0;
        int incl = v;
#pragma unroll
        for (int o = 1; o < 64; o <<= 1) {
            int t = __shfl_up(incl, o, 64);
            if (lane >= o) incl += t;
        }
        if (lane == 63) wsum[wid] = incl;
        __syncthreads();
        if (wid == 0 && lane < 16) {
            int t = wsum[lane];
            int inc2 = t;
#pragma unroll
            for (int o = 1; o < 16; o <<= 1) {
                int u = __shfl_up(inc2, o, 64);
                if (lane >= o) inc2 += u;
            }
            woff[lane] = inc2 - t;
            if (lane == 15) tile_tot = inc2;
        }
        __syncthreads();
        int c = carry;
        if (i < N_NODES) {
            int o = c + woff[wid] + (incl - v);
            off[i] = o;
            cnt_cur[i] = o;
        }
        __syncthreads();
        if (threadIdx.x == 0) carry = c + tile_tot;
        __syncthreads();
    }
    if (threadIdx.x == 0) off[N_NODES] = carry;
}

__global__ void fillc_kernel(const int* __restrict__ ei, const int* __restrict__ flag,
                             int* __restrict__ cur, int* __restrict__ srcs) {
    int e = blockIdx.x * blockDim.x + threadIdx.x;
    if (e >= N_EDGES) return;
    int is32 = flag[0];
    int d = load_dst(ei, is32, e);
    int p = atomicAdd(&cur[d], 1);
    srcs[p] = load_src(ei, is32, e);
}

__global__ __launch_bounds__(256) void aggc_kernel(const unsigned short* __restrict__ feat,
                                                   const int* __restrict__ off,
                                                   const int* __restrict__ srcs,
                                                   unsigned short* __restrict__ agg) {
    int node = blockIdx.x * 4 + (threadIdx.x >> 6);
    if (node >= N_NODES) return;
    int lane = threadIdx.x & 63;
    int half = lane >> 5;
    int c8 = lane & 31;
    int s0 = off[node], s1 = off[node + 1];
    int deg = s1 - s0;
    float a0 = 0.f, a1 = 0.f, a2 = 0.f, a3 = 0.f;
    for (int j = s0; j < s1; j += 2) {
        int jj = j + half;
        if (jj < s1) {
            int e = srcs[jj];
            u16x4 v = *((const u16x4*)(feat + (size_t)e * D) + c8);
            a0 += bf2f((unsigned short)v[0]);
            a1 += bf2f((unsigned short)v[1]);
            a2 += bf2f((unsigned short)v[2]);
            a3 += bf2f((unsigned short)v[3]);
        }
    }
    a0 += __shfl_xor(a0, 32, 64);
    a1 += __shfl_xor(a1, 32, 64);
    a2 += __shfl_xor(a2, 32, 64);
    a3 += __shfl_xor(a3, 32, 64);
    if (half == 0) {
        float s = deg > 0 ? 1.f / (float)deg : 0.f;
        u16x4 o;
        o[0] = f2bf(a0 * s); o[1] = f2bf(a1 * s);
        o[2] = f2bf(a2 * s); o[3] = f2bf(a3 * s);
        *((u16x4*)(agg + (size_t)node * D) + c8) = o;
    }
}

// ---------------------------------------------------------------------------
extern "C" void kernel_launch(void* const* d_in, const int* in_sizes, int n_in,
                              void* d_out, int out_size, void* d_ws, size_t ws_size,
                              hipStream_t stream) {
    const float* x = (const float*)d_in[0];
    const int* ei = (const int*)d_in[1];
    const float* W1l = (const float*)d_in[2];
    const float* b1 = (const float*)d_in[3];
    const float* W1r = (const float*)d_in[4];
    const float* W2l = (const float*)d_in[5];
    const float* b2 = (const float*)d_in[6];
    const float* W2r = (const float*)d_in[7];
    float* out = (float*)d_out;

    // padded layout: flag 256 | bin_cnt 512 | bins 4.8M | srcs16 6.4M | cnt 200K
    // | wt1 64K | wt2 64K | xb 12.8M | hb 12.8M | aggb 12.8M
    const size_t padded_need = 256 + 512 + (size_t)NBIN * BIN_CAP * 4 +
                               (size_t)50176 * CAP * 2 + 50048 * 4 + 2 * 65536 +
                               3 * (size_t)N_NODES * D * 2;

    if (ws_size >= padded_need) {
        char* w = (char*)d_ws;
        int* flag = (int*)w;                      w += 256;
        int* bin_cnt = (int*)w;                   w += 512;
        unsigned* bins = (unsigned*)w;            w += (size_t)NBIN * BIN_CAP * 4;
        unsigned short* srcs16 = (unsigned short*)w; w += (size_t)50176 * CAP * 2;
        int* cnt = (int*)w;                       w += 50048 * 4;
        unsigned short* wt1 = (unsigned short*)w; w += 65536;
        unsigned short* wt2 = (unsigned short*)w; w += 65536;
        unsigned short* xb = (unsigned short*)w;  w += (size_t)N_NODES * D * 2;
        unsigned short* hb = (unsigned short*)w;  w += (size_t)N_NODES * D * 2;
        unsigned short* aggb = (unsigned short*)w;

        prep_kernel<<<3382, 256, 0, stream>>>(x, ei, W1l, W1r, W2l, W2r, xb, wt1, wt2,
                                              flag, bin_cnt);
        binp_kernel<<<(N_EDGES + EPB - 1) / EPB, 256, 0, stream>>>(ei, flag, bin_cnt, bins);
        unbin_kernel<<<NBIN, 256, 0, stream>>>(bin_cnt, bins, cnt, srcs16);

        int nblk = (N_NODES + 31) / 32;
        int agrid = (N_NODES / 2 + 3) / 4;  // 2 nodes/wave, 4 waves/block
        aggp_kernel<<<agrid, 256, 0, stream>>>(xb, cnt, srcs16, aggb);
        mm3_kernel<1><<<nblk, 256, 0, stream>>>(aggb, xb, wt1, b1, nullptr, hb);

        aggp_kernel<<<agrid, 256, 0, stream>>>(hb, cnt, srcs16, aggb);
        mm3_kernel<2><<<nblk, 256, 0, stream>>>(aggb, hb, wt2, b2, out, nullptr);
    } else {
        // compact CSR fallback (xb doubles as h storage after layer-1 gather)
        char* w = (char*)d_ws;
        int* flag = (int*)w;                      w += 256;
        int* cur = (int*)w;                       w += 50048 * 4;
        int* off = (int*)w;                       w += 50056 * 4;
        int* srcs = (int*)w;                      w += (size_t)N_EDGES * 4;
        unsigned short* wt1 = (unsigned short*)w; w += 65536;
        unsigned short* wt2 = (unsigned short*)w; w += 65536;
        unsigned short* xb = (unsigned short*)w;  w += (size_t)N_NODES * D * 2;
        unsigned short* aggb = (unsigned short*)w;

        initc_kernel<<<196, 256, 0, stream>>>(ei, flag, cur);
        prep_wf_kernel<<<256, 256, 0, stream>>>(W1l, W1r, W2l, W2r, wt1, wt2);
        tobf_kernel<<<(N_NODES * D / 8 + 255) / 256, 256, 0, stream>>>(x, xb, N_NODES * D / 8);
        hist_kernel<<<(N_EDGES + 255) / 256, 256, 0, stream>>>(ei, flag, cur);
        scan_kernel<<<1, 1024, 0, stream>>>(cur, off);
        fillc_kernel<<<(N_EDGES + 255) / 256, 256, 0, stream>>>(ei, flag, cur, srcs);

        int nblk = (N_NODES + 31) / 32;
        aggc_kernel<<<(N_NODES + 3) / 4, 256, 0, stream>>>(xb, off, srcs, aggb);
        // in-place xb->h safe: each block reads only its own rows before writing them
        mm3_kernel<1><<<nblk, 256, 0, stream>>>(aggb, xb, wt1, b1, nullptr, xb);

        aggc_kernel<<<(N_NODES + 3) / 4, 256, 0, stream>>>(xb, off, srcs, aggb);
        mm3_kernel<2><<<nblk, 256, 0, stream>>>(aggb, xb, wt2, b2, out, nullptr);
    }
}

// Round 10
// 126.517 us; speedup vs baseline: 1.0747x; 1.0747x over previous
//
#include <hip/hip_runtime.h>

#define N_NODES 50000
#define N_EDGES 800000
#define D 128
#define CAP 64
#define NPB 512        // nodes per bin: bin = dst >> 9
#define NBIN 98        // ceil(50000/512)
#define BIN_CAP 12288  // per-bin edge capacity (mean 8163)
#define EPB 4096       // edges per binp block

typedef __attribute__((ext_vector_type(8))) short s16x8;
typedef __attribute__((ext_vector_type(8))) unsigned short u16x8;
typedef __attribute__((ext_vector_type(4))) unsigned short u16x4;
typedef __attribute__((ext_vector_type(4))) float f32x4;

__device__ __forceinline__ unsigned short f2bf(float f) {
    unsigned u = __builtin_bit_cast(unsigned, f);
    return (unsigned short)((u + 0x7FFFu + ((u >> 16) & 1u)) >> 16);
}
__device__ __forceinline__ float bf2f(unsigned short h) {
    return __builtin_bit_cast(float, (unsigned)h << 16);
}

__device__ __forceinline__ int load_src(const int* ei, int is32, int e) {
    return is32 ? ei[e] : ei[2 * e];
}
__device__ __forceinline__ int load_dst(const int* ei, int is32, int e) {
    return is32 ? ei[N_EDGES + e] : ei[2 * N_EDGES + 2 * e];
}

// ---------------------------------------------------------------------------
// Merged prep: blocks 0..3124 = x->bf16; 3125..3380 = W tables (bf16 RN,
// layout [col(128)][k(256)]); 3381 = zero bin_cnt + ei dtype detect.
__global__ void prep_kernel(const float* __restrict__ x, const int* __restrict__ ei,
                            const float* __restrict__ W1l, const float* __restrict__ W1r,
                            const float* __restrict__ W2l, const float* __restrict__ W2r,
                            unsigned short* __restrict__ xb,
                            unsigned short* __restrict__ wt1,
                            unsigned short* __restrict__ wt2,
                            int* __restrict__ flag, int* __restrict__ bin_cnt) {
    int b = blockIdx.x;
    if (b < 3125) {
        int t = b * 256 + threadIdx.x;  // t < 800000 == 3125*256
        float4 a = *(const float4*)(x + (size_t)t * 8);
        float4 c = *(const float4*)(x + (size_t)t * 8 + 4);
        u16x8 o;
        o[0] = f2bf(a.x); o[1] = f2bf(a.y); o[2] = f2bf(a.z); o[3] = f2bf(a.w);
        o[4] = f2bf(c.x); o[5] = f2bf(c.y); o[6] = f2bf(c.z); o[7] = f2bf(c.w);
        *(u16x8*)(xb + (size_t)t * 8) = o;
    } else if (b < 3381) {
        int idx = b - 3125;  // 0..255
        int layer = idx >> 7;
        int c = idx & 127;
        int k = threadIdx.x;
        const float* Wl = layer ? W2l : W1l;
        const float* Wr = layer ? W2r : W1r;
        unsigned short* wt = layer ? wt2 : wt1;
        float v = (k < 128) ? Wl[(size_t)k * 128 + c] : Wr[(size_t)(k - 128) * 128 + c];
        wt[c * 256 + k] = f2bf(v);
    } else {
        if (threadIdx.x < 128) bin_cnt[threadIdx.x] = 0;
        __shared__ int any;
        if (threadIdx.x == 0) any = 0;
        __syncthreads();
        if (ei[2 * threadIdx.x + 1] != 0) atomicOr(&any, 1);
        __syncthreads();
        if (threadIdx.x == 0) flag[0] = any;
    }
}

// ---------------------------------------------------------------------------
// Pass 1: bin edges by dst>>9 into 98 global bins; packed (dst16|src16).
__global__ __launch_bounds__(256) void binp_kernel(const int* __restrict__ ei,
                                                   const int* __restrict__ flag,
                                                   int* __restrict__ bin_cnt,
                                                   unsigned* __restrict__ bins) {
    __shared__ unsigned sBuf[EPB];
    __shared__ int bcnt[128], brun[128], bpos[128], gbase[128];
    int tid = threadIdx.x;
    int blk = blockIdx.x;
    int e0 = blk * EPB + tid * 16;
    int nblk = N_EDGES - blk * EPB;
    if (nblk > EPB) nblk = EPB;
    bool valid = (tid * 16) < nblk;
    if (tid < 128) bcnt[tid] = 0;
    __syncthreads();
    unsigned packed[16];
    if (valid) {
        int is32 = flag[0];
        if (is32) {
            const int4* ps = (const int4*)(ei + e0);
            const int4* pd = (const int4*)(ei + N_EDGES + e0);
#pragma unroll
            for (int q = 0; q < 4; ++q) {
                int4 s = ps[q], d = pd[q];
                packed[q * 4 + 0] = ((unsigned)d.x << 16) | (unsigned)s.x;
                packed[q * 4 + 1] = ((unsigned)d.y << 16) | (unsigned)s.y;
                packed[q * 4 + 2] = ((unsigned)d.z << 16) | (unsigned)s.z;
                packed[q * 4 + 3] = ((unsigned)d.w << 16) | (unsigned)s.w;
            }
        } else {
            const int4* ps = (const int4*)(ei + 2 * (size_t)e0);
            const int4* pd = (const int4*)(ei + 2 * (size_t)N_EDGES + 2 * (size_t)e0);
#pragma unroll
            for (int q = 0; q < 8; ++q) {
                int4 s = ps[q], d = pd[q];
                packed[q * 2 + 0] = ((unsigned)d.x << 16) | (unsigned)s.x;
                packed[q * 2 + 1] = ((unsigned)d.z << 16) | (unsigned)s.z;
            }
        }
#pragma unroll
        for (int k = 0; k < 16; ++k) atomicAdd(&bcnt[packed[k] >> 25], 1);
    }
    __syncthreads();
    if (tid < 64) {
        int a = bcnt[2 * tid], b = bcnt[2 * tid + 1];
        int s = a + b;
        int incl = s;
#pragma unroll
        for (int o = 1; o < 64; o <<= 1) {
            int t = __shfl_up(incl, o, 64);
            if (tid >= o) incl += t;
        }
        int pref = incl - s;
        brun[2 * tid] = pref;
        brun[2 * tid + 1] = pref + a;
        bpos[2 * tid] = pref;
        bpos[2 * tid + 1] = pref + a;
    }
    __syncthreads();
    if (valid) {
#pragma unroll
        for (int k = 0; k < 16; ++k) {
            int b = packed[k] >> 25;
            int slot = atomicAdd(&bpos[b], 1);
            sBuf[slot] = packed[k];
        }
    }
    __syncthreads();
    if (tid < 128) {
        int n = bcnt[tid];
        gbase[tid] = n > 0 ? atomicAdd(&bin_cnt[tid], n) : 0;
    }
    __syncthreads();
    for (int i = tid; i < nblk; i += 256) {
        unsigned p = sBuf[i];
        int b = p >> 25;
        int gpos = gbase[b] + (i - brun[b]);
        if (gpos < BIN_CAP) bins[(size_t)b * BIN_CAP + gpos] = p;
    }
}

// Pass 2: one block per bin; buckets in LDS; dense coalesced write-out.
__global__ __launch_bounds__(256) void unbin_kernel(const int* __restrict__ bin_cnt,
                                                    const unsigned* __restrict__ bins,
                                                    int* __restrict__ cnt,
                                                    unsigned short* __restrict__ srcs16) {
    __shared__ unsigned short buck[NPB * CAP];
    __shared__ int lcnt[NPB];
    int tid = threadIdx.x;
    int bn = blockIdx.x;
    int nbase = bn * NPB;
    for (int i = tid; i < NPB; i += 256) lcnt[i] = 0;
    __syncthreads();
    int nE = bin_cnt[bn];
    if (nE > BIN_CAP) nE = BIN_CAP;
    for (int i = tid; i < nE; i += 256) {
        unsigned p = bins[(size_t)bn * BIN_CAP + i];
        int local = (int)(p >> 16) - nbase;
        if ((unsigned)local < NPB) {
            int slot = atomicAdd(&lcnt[local], 1);
            if (slot < CAP) buck[local * CAP + slot] = (unsigned short)(p & 0xFFFFu);
        }
    }
    __syncthreads();
    int nlim = N_NODES - nbase;
    if (nlim > NPB) nlim = NPB;
    const uint4* sb = (const uint4*)buck;
    uint4* go = (uint4*)(srcs16 + (size_t)nbase * CAP);
    int n4 = nlim * 8;
    for (int i = tid; i < n4; i += 256) go[i] = sb[i];
    for (int i = tid; i < nlim; i += 256) cnt[nbase + i] = lcnt[i];
}

// ---------------------------------------------------------------------------
// FUSED layer: 512 thr = 8 waves, 32-row tile.
// Phase A (no barrier): issue root-row load; preload B frags (8 x 16B regs);
//   each wave gather-means 4 nodes (R7 pattern: bucket in regs, 16 edges in
//   flight) -> means written to LDS sA[0]; root regs -> sA[1]. ONE barrier.
// Phase B: 16 MFMAs/wave (16 cols each), bias(+relu), store.
// MODE 1: out = bf16 h -> Cb.  MODE 2: out = f32 -> C.
template <int MODE>
__global__ __launch_bounds__(512, 4) void fused_kernel(
    const unsigned short* __restrict__ feat,   // gather table (= root buffer)
    const int* __restrict__ cnt,
    const unsigned short* __restrict__ srcs16,
    const unsigned short* __restrict__ Wt,
    const float* __restrict__ bias,
    float* __restrict__ C, unsigned short* __restrict__ Cb) {
    __shared__ __align__(16) unsigned short sA[2][32][128];  // [0]=agg [1]=root
    int r0 = blockIdx.x * 32;
    int tid = threadIdx.x;
    int lane = tid & 63, wid = tid >> 6;  // wid 0..7
    int l15 = lane & 15, khalf = lane >> 4;

    // ---- root-row load (issue first; LDS write deferred to after gather)
    int rr_ = tid >> 4, rkq = tid & 15;
    int rowX = r0 + rr_;
    u16x8 vroot = {};
    if (rowX < N_NODES)
        vroot = *(const u16x8*)(feat + (size_t)rowX * D + rkq * 8);

    // ---- B frag preload (wave's 16 cols; hides under gather)
    s16x8 bF[2][4];
#pragma unroll
    for (int p = 0; p < 2; ++p)
#pragma unroll
        for (int kc2 = 0; kc2 < 4; ++kc2)
            bF[p][kc2] = *(const s16x8*)(Wt + (size_t)(wid * 16 + l15) * 256 +
                                         p * 128 + kc2 * 32 + khalf * 8);

    // ---- gather: wave wid owns nodes nb..nb+3 (1 node at a time, R7 pattern)
    {
        int nb = r0 + wid * 4;
        int q = lane >> 4, c16 = lane & 15;
        int4 d4 = *(const int4*)(cnt + nb);  // nb % 4 == 0
        int degs[4] = {d4.x, d4.y, d4.z, d4.w};
        int idxA[4];
#pragma unroll
        for (int k = 0; k < 4; ++k)
            idxA[k] = srcs16[(size_t)(nb + k) * CAP + lane];
#pragma unroll
        for (int k = 0; k < 4; ++k) {
            int node = nb + k;
            int deg = (node < N_NODES) ? degs[k] : 0;
            int dd = deg < CAP ? deg : CAP;
            float acc[8] = {};
            for (int j = 0; j < dd; j += 16) {
                int e[4];
                float m[4];
#pragma unroll
                for (int u = 0; u < 4; ++u) {
                    int jj = j + u * 4 + q;
                    int es = __shfl(idxA[k], jj, 64);
                    bool val = jj < dd;
                    e[u] = val ? es : 0;
                    m[u] = val ? 1.f : 0.f;
                }
                u16x8 v[4];
#pragma unroll
                for (int u = 0; u < 4; ++u)
                    v[u] = *((const u16x8*)(feat + (size_t)e[u] * D) + c16);
#pragma unroll
                for (int u = 0; u < 4; ++u)
#pragma unroll
                    for (int i = 0; i < 8; ++i)
                        acc[i] += bf2f((unsigned short)v[u][i]) * m[u];
            }
#pragma unroll
            for (int i = 0; i < 8; ++i) {
                acc[i] += __shfl_xor(acc[i], 16, 64);
                acc[i] += __shfl_xor(acc[i], 32, 64);
            }
            if (q == 0 && node < N_NODES) {
                float s = deg > 0 ? 1.f / (float)deg : 0.f;
                u16x8 o;
#pragma unroll
                for (int i = 0; i < 8; ++i) o[i] = f2bf(acc[i] * s);
                int lr = wid * 4 + k;
                *(u16x8*)&sA[0][lr][(c16 ^ (lr & 7)) * 8] = o;
            }
        }
    }

    // ---- root reg -> LDS (swizzled), then the one barrier
    *(u16x8*)&sA[1][rr_][(rkq ^ (rr_ & 7)) * 8] = vroot;
    __syncthreads();

    // ---- MFMA: p=0 agg, p=1 root; pure LDS + regs
    f32x4 acc2[2] = {};
#pragma unroll
    for (int p = 0; p < 2; ++p)
#pragma unroll
        for (int kc2 = 0; kc2 < 4; ++kc2) {
            s16x8 aF[2];
#pragma unroll
            for (int mf = 0; mf < 2; ++mf) {
                int rr = mf * 16 + l15;
                int chunk = (kc2 * 4 + khalf) ^ (rr & 7);
                aF[mf] = *(const s16x8*)&sA[p][rr][chunk * 8];
            }
#pragma unroll
            for (int mf = 0; mf < 2; ++mf)
                acc2[mf] = __builtin_amdgcn_mfma_f32_16x16x32_bf16(
                    aF[mf], bF[p][kc2], acc2[mf], 0, 0, 0);
        }

    // ---- epilogue: C/D layout col=lane&15, row=(lane>>4)*4+reg (m89-verified)
    {
        int col = wid * 16 + l15;
        float b = bias[col];
#pragma unroll
        for (int mf = 0; mf < 2; ++mf)
#pragma unroll
            for (int r = 0; r < 4; ++r) {
                int row = r0 + mf * 16 + khalf * 4 + r;
                if (row < N_NODES) {
                    float o = acc2[mf][r] + b;
                    if (MODE == 1) {
                        o = fmaxf(o, 0.f);
                        Cb[(size_t)row * D + col] = f2bf(o);
                    } else {
                        C[(size_t)row * D + col] = o;
                    }
                }
            }
    }
}

// ---------------------------------------------------------------------------
// ---- compact CSR fallback kernels (only if ws too small) -------------------
__global__ void initc_kernel(const int* __restrict__ ei, int* __restrict__ flag,
                             int* __restrict__ cnt) {
    int i = blockIdx.x * 256 + threadIdx.x;
    if (i < 50048) cnt[i] = 0;
    if (blockIdx.x == 0) {
        __shared__ int any;
        if (threadIdx.x == 0) any = 0;
        __syncthreads();
        if (ei[2 * threadIdx.x + 1] != 0) atomicOr(&any, 1);
        __syncthreads();
        if (threadIdx.x == 0) flag[0] = any;
    }
}

__global__ void prep_wf_kernel(const float* __restrict__ W1l, const float* __restrict__ W1r,
                               const float* __restrict__ W2l, const float* __restrict__ W2r,
                               unsigned short* __restrict__ wt1,
                               unsigned short* __restrict__ wt2) {
    int layer = blockIdx.x >> 7;
    int c = blockIdx.x & 127;
    int k = threadIdx.x;
    const float* Wl = layer ? W2l : W1l;
    const float* Wr = layer ? W2r : W1r;
    unsigned short* wt = layer ? wt2 : wt1;
    float v = (k < 128) ? Wl[(size_t)k * 128 + c] : Wr[(size_t)(k - 128) * 128 + c];
    wt[c * 256 + k] = f2bf(v);
}

__global__ void tobf_kernel(const float* __restrict__ in, unsigned short* __restrict__ out,
                            int n8) {
    int t = blockIdx.x * 256 + threadIdx.x;
    if (t >= n8) return;
    float4 a = *(const float4*)(in + (size_t)t * 8);
    float4 b = *(const float4*)(in + (size_t)t * 8 + 4);
    u16x8 o;
    o[0] = f2bf(a.x); o[1] = f2bf(a.y); o[2] = f2bf(a.z); o[3] = f2bf(a.w);
    o[4] = f2bf(b.x); o[5] = f2bf(b.y); o[6] = f2bf(b.z); o[7] = f2bf(b.w);
    *(u16x8*)(out + (size_t)t * 8) = o;
}

__global__ void hist_kernel(const int* __restrict__ ei, const int* __restrict__ flag,
                            int* __restrict__ cnt) {
    int e = blockIdx.x * blockDim.x + threadIdx.x;
    if (e >= N_EDGES) return;
    int is32 = flag[0];
    atomicAdd(&cnt[load_dst(ei, is32, e)], 1);
}

__global__ __launch_bounds__(1024) void scan_kernel(int* __restrict__ cnt_cur,
                                                    int* __restrict__ off) {
    __shared__ int wsum[16];
    __shared__ int woff[16];
    __shared__ int carry;
    __shared__ int tile_tot;
    int lane = threadIdx.x & 63;
    int wid = threadIdx.x >> 6;
    if (threadIdx.x == 0) carry = 0;
    __syncthreads();
    for (int base = 0; base < N_NODES; base += 1024) {
        int i = base + threadIdx.x;
        int v = (i < N_NODES) ? cnt_cur[i] : 0;
        int incl = v;
#pragma unroll
        for (int o = 1; o < 64; o <<= 1) {
            int t = __shfl_up(incl, o, 64);
            if (lane >= o) incl += t;
        }
        if (lane == 63) wsum[wid] = incl;
        __syncthreads();
        if (wid == 0 && lane < 16) {
            int t = wsum[lane];
            int inc2 = t;
#pragma unroll
            for (int o = 1; o < 16; o <<= 1) {
                int u = __shfl_up(inc2, o, 64);
                if (lane >= o) inc2 += u;
            }
            woff[lane] = inc2 - t;
            if (lane == 15) tile_tot = inc2;
        }
        __syncthreads();
        int c = carry;
        if (i < N_NODES) {
            int o = c + woff[wid] + (incl - v);
            off[i] = o;
            cnt_cur[i] = o;
        }
        __syncthreads();
        if (threadIdx.x == 0) carry = c + tile_tot;
        __syncthreads();
    }
    if (threadIdx.x == 0) off[N_NODES] = carry;
}

__global__ void fillc_kernel(const int* __restrict__ ei, const int* __restrict__ flag,
                             int* __restrict__ cur, int* __restrict__ srcs) {
    int e = blockIdx.x * blockDim.x + threadIdx.x;
    if (e >= N_EDGES) return;
    int is32 = flag[0];
    int d = load_dst(ei, is32, e);
    int p = atomicAdd(&cur[d], 1);
    srcs[p] = load_src(ei, is32, e);
}

__global__ __launch_bounds__(256) void aggc_kernel(const unsigned short* __restrict__ feat,
                                                   const int* __restrict__ off,
                                                   const int* __restrict__ srcs,
                                                   unsigned short* __restrict__ agg) {
    int node = blockIdx.x * 4 + (threadIdx.x >> 6);
    if (node >= N_NODES) return;
    int lane = threadIdx.x & 63;
    int half = lane >> 5;
    int c8 = lane & 31;
    int s0 = off[node], s1 = off[node + 1];
    int deg = s1 - s0;
    float a0 = 0.f, a1 = 0.f, a2 = 0.f, a3 = 0.f;
    for (int j = s0; j < s1; j += 2) {
        int jj = j + half;
        if (jj < s1) {
            int e = srcs[jj];
            u16x4 v = *((const u16x4*)(feat + (size_t)e * D) + c8);
            a0 += bf2f((unsigned short)v[0]);
            a1 += bf2f((unsigned short)v[1]);
            a2 += bf2f((unsigned short)v[2]);
            a3 += bf2f((unsigned short)v[3]);
        }
    }
    a0 += __shfl_xor(a0, 32, 64);
    a1 += __shfl_xor(a1, 32, 64);
    a2 += __shfl_xor(a2, 32, 64);
    a3 += __shfl_xor(a3, 32, 64);
    if (half == 0) {
        float s = deg > 0 ? 1.f / (float)deg : 0.f;
        u16x4 o;
        o[0] = f2bf(a0 * s); o[1] = f2bf(a1 * s);
        o[2] = f2bf(a2 * s); o[3] = f2bf(a3 * s);
        *((u16x4*)(agg + (size_t)node * D) + c8) = o;
    }
}

// fallback standalone GEMM (32-row tile, reg-preloaded B)
template <int MODE>
__global__ __launch_bounds__(256) void mm3_kernel(const unsigned short* __restrict__ Agb,
                                                  const unsigned short* __restrict__ Rootb,
                                                  const unsigned short* __restrict__ Wt,
                                                  const float* __restrict__ bias,
                                                  float* __restrict__ C,
                                                  unsigned short* __restrict__ Cb) {
    __shared__ __align__(16) unsigned short sA[2][32][128];
    int r0 = blockIdx.x * 32;
    int tid = threadIdx.x;
    int lane = tid & 63, wid = tid >> 6;
    int l15 = lane & 15, khalf = lane >> 4;

    s16x8 bF[2][4][2];
#pragma unroll
    for (int p = 0; p < 2; ++p)
#pragma unroll
        for (int kc2 = 0; kc2 < 4; ++kc2)
#pragma unroll
            for (int nf = 0; nf < 2; ++nf) {
                int cc = wid * 32 + nf * 16 + l15;
                bF[p][kc2][nf] = *(const s16x8*)(Wt + (size_t)cc * 256 + p * 128 +
                                                 kc2 * 32 + khalf * 8);
            }
    {
        int r = tid >> 3;
        int kq = tid & 7;
        int row = r0 + r;
        u16x8 a0, a1, x0, x1;
        if (row < N_NODES) {
            const u16x8* pa = (const u16x8*)(Agb + (size_t)row * D + kq * 16);
            a0 = pa[0]; a1 = pa[1];
            const u16x8* pr = (const u16x8*)(Rootb + (size_t)row * D + kq * 16);
            x0 = pr[0]; x1 = pr[1];
        } else {
            u16x8 z = {};
            a0 = z; a1 = z; x0 = z; x1 = z;
        }
        int c0 = (kq * 2) ^ (r & 7), c1 = (kq * 2 + 1) ^ (r & 7);
        *(u16x8*)&sA[0][r][c0 * 8] = a0;
        *(u16x8*)&sA[0][r][c1 * 8] = a1;
        *(u16x8*)&sA[1][r][c0 * 8] = x0;
        *(u16x8*)&sA[1][r][c1 * 8] = x1;
    }
    __syncthreads();

    f32x4 acc[2][2] = {};
#pragma unroll
    for (int p = 0; p < 2; ++p)
#pragma unroll
        for (int kc2 = 0; kc2 < 4; ++kc2) {
            s16x8 aF[2];
#pragma unroll
            for (int mf = 0; mf < 2; ++mf) {
                int rr = mf * 16 + l15;
                int chunk = (kc2 * 4 + khalf) ^ (rr & 7);
                aF[mf] = *(const s16x8*)&sA[p][rr][chunk * 8];
            }
#pragma unroll
            for (int nf = 0; nf < 2; ++nf)
#pragma unroll
                for (int mf = 0; mf < 2; ++mf)
                    acc[mf][nf] = __builtin_amdgcn_mfma_f32_16x16x32_bf16(
                        aF[mf], bF[p][kc2][nf], acc[mf][nf], 0, 0, 0);
        }

#pragma unroll
    for (int mf = 0; mf < 2; ++mf)
#pragma unroll
        for (int nf = 0; nf < 2; ++nf) {
            int col = wid * 32 + nf * 16 + l15;
            float b = bias[col];
#pragma unroll
            for (int r = 0; r < 4; ++r) {
                int row = r0 + mf * 16 + khalf * 4 + r;
                if (row < N_NODES) {
                    float o = acc[mf][nf][r] + b;
                    if (MODE == 1) {
                        o = fmaxf(o, 0.f);
                        Cb[(size_t)row * D + col] = f2bf(o);
                    } else {
                        C[(size_t)row * D + col] = o;
                    }
                }
            }
        }
}

// ---------------------------------------------------------------------------
extern "C" void kernel_launch(void* const* d_in, const int* in_sizes, int n_in,
                              void* d_out, int out_size, void* d_ws, size_t ws_size,
                              hipStream_t stream) {
    const float* x = (const float*)d_in[0];
    const int* ei = (const int*)d_in[1];
    const float* W1l = (const float*)d_in[2];
    const float* b1 = (const float*)d_in[3];
    const float* W1r = (const float*)d_in[4];
    const float* W2l = (const float*)d_in[5];
    const float* b2 = (const float*)d_in[6];
    const float* W2r = (const float*)d_in[7];
    float* out = (float*)d_out;

    // padded layout: flag 256 | bin_cnt 512 | bins 4.8M | srcs16 6.4M | cnt 200K
    // | wt1 64K | wt2 64K | xb 12.8M | hb 12.8M
    const size_t padded_need = 256 + 512 + (size_t)NBIN * BIN_CAP * 4 +
                               (size_t)50176 * CAP * 2 + 50048 * 4 + 2 * 65536 +
                               2 * (size_t)N_NODES * D * 2;

    if (ws_size >= padded_need) {
        char* w = (char*)d_ws;
        int* flag = (int*)w;                      w += 256;
        int* bin_cnt = (int*)w;                   w += 512;
        unsigned* bins = (unsigned*)w;            w += (size_t)NBIN * BIN_CAP * 4;
        unsigned short* srcs16 = (unsigned short*)w; w += (size_t)50176 * CAP * 2;
        int* cnt = (int*)w;                       w += 50048 * 4;
        unsigned short* wt1 = (unsigned short*)w; w += 65536;
        unsigned short* wt2 = (unsigned short*)w; w += 65536;
        unsigned short* xb = (unsigned short*)w;  w += (size_t)N_NODES * D * 2;
        unsigned short* hb = (unsigned short*)w;

        prep_kernel<<<3382, 256, 0, stream>>>(x, ei, W1l, W1r, W2l, W2r, xb, wt1, wt2,
                                              flag, bin_cnt);
        binp_kernel<<<(N_EDGES + EPB - 1) / EPB, 256, 0, stream>>>(ei, flag, bin_cnt, bins);
        unbin_kernel<<<NBIN, 256, 0, stream>>>(bin_cnt, bins, cnt, srcs16);

        int nblk = (N_NODES + 31) / 32;
        fused_kernel<1><<<nblk, 512, 0, stream>>>(xb, cnt, srcs16, wt1, b1, nullptr, hb);
        fused_kernel<2><<<nblk, 512, 0, stream>>>(hb, cnt, srcs16, wt2, b2, out, nullptr);
    } else {
        // compact CSR fallback (xb doubles as h storage after layer-1 gather)
        char* w = (char*)d_ws;
        int* flag = (int*)w;                      w += 256;
        int* cur = (int*)w;                       w += 50048 * 4;
        int* off = (int*)w;                       w += 50056 * 4;
        int* srcs = (int*)w;                      w += (size_t)N_EDGES * 4;
        unsigned short* wt1 = (unsigned short*)w; w += 65536;
        unsigned short* wt2 = (unsigned short*)w; w += 65536;
        unsigned short* xb = (unsigned short*)w;  w += (size_t)N_NODES * D * 2;
        unsigned short* aggb = (unsigned short*)w;

        initc_kernel<<<196, 256, 0, stream>>>(ei, flag, cur);
        prep_wf_kernel<<<256, 256, 0, stream>>>(W1l, W1r, W2l, W2r, wt1, wt2);
        tobf_kernel<<<(N_NODES * D / 8 + 255) / 256, 256, 0, stream>>>(x, xb, N_NODES * D / 8);
        hist_kernel<<<(N_EDGES + 255) / 256, 256, 0, stream>>>(ei, flag, cur);
        scan_kernel<<<1, 1024, 0, stream>>>(cur, off);
        fillc_kernel<<<(N_EDGES + 255) / 256, 256, 0, stream>>>(ei, flag, cur, srcs);

        int nblk = (N_NODES + 31) / 32;
        aggc_kernel<<<(N_NODES + 3) / 4, 256, 0, stream>>>(xb, off, srcs, aggb);
        mm3_kernel<1><<<nblk, 256, 0, stream>>>(aggb, xb, wt1, b1, nullptr, xb);

        aggc_kernel<<<(N_NODES + 3) / 4, 256, 0, stream>>>(xb, off, srcs, aggb);
        mm3_kernel<2><<<nblk, 256, 0, stream>>>(aggb, xb, wt2, b2, out, nullptr);
    }
}